// Round 9
// baseline (152.450 us; speedup 1.0000x reference)
//
#include <hip/hip_runtime.h>
#include <hip/hip_bf16.h>
#include <stdint.h>

// ZoeDepth attractor head, R10: TLP over pipelining. R7/R9 post-mortem: four
// structures land 47-61us with every pipe <25% and occupancy ~24% — a pure
// latency wall at 4096 waves (16/CU, 4/SIMD). Intra-wave pipelining can't fix
// wave count; m69's VGPR bands (>64 regs => <=16 waves/CU) made pipeline and
// occupancy mutually exclusive. R10 o-splits each 16-px column across TWO
// waves (A: o0-63, B: o64-127, all 256 ch => per-output accumulation order
// bit-identical to R9). 8192 waves, 512-thr blocks, 4 blocks/CU = 32
// waves/CU (8/SIMD). All loads plain HIP (<=64 VGPR, no asm-spill hazard);
// 8-deep wave TLP hides latency instead. x read 2x per px-group: wave-pair
// is co-resident => partner hits L1/L2, FETCH unchanged. 2 __syncthreads.

#define HW 16384
#define ALPHA 300.0f
#define EXP2K -432.8085122666891f  // -ALPHA * log2(e)

typedef short bf16x8_t __attribute__((ext_vector_type(8)));
typedef float f32x4_t __attribute__((ext_vector_type(4)));
typedef float f32x2_t __attribute__((ext_vector_type(2)));
typedef unsigned int u32x4_t __attribute__((ext_vector_type(4)));

__device__ __forceinline__ unsigned short f2bf(float f) {
  unsigned int u = __builtin_bit_cast(unsigned int, f);
  u += 0x7fffu + ((u >> 16) & 1u);
  return (unsigned short)(u >> 16);
}
// hardware packed f32->bf16 (RNE), one VALU op for two elements
__device__ __forceinline__ unsigned int cvtpk(float lo, float hi) {
  unsigned int r;
  asm("v_cvt_pk_bf16_f32 %0, %1, %2" : "=v"(r) : "v"(lo), "v"(hi));
  return r;
}
// 2^x (arg already in log2 domain)
__device__ __forceinline__ float exp2a(float x) {
  float r;
  asm("v_exp_f32 %0, %1" : "=v"(r) : "v"(x));
  return r;
}

// ---------------------------------------------------------------------------
// Prep: w1 (128x256) and w2 (16x128) fp32 -> bf16 blobs in frag layout,
// 16B granules XOR-swizzled by (row&3). w1: 8 chunks x 8192 B @0.
// w2: 4 chunks x 1024 B @byte 65536.  (unchanged, verified)
// ---------------------------------------------------------------------------
__global__ void zoed_prep(const float* __restrict__ w1,
                          const float* __restrict__ w2,
                          unsigned short* __restrict__ blob) {
  int i = blockIdx.x * 256 + threadIdx.x;  // 136*256 = 34816 = 32768 + 2048
  if (i < 32768) {
    int o = i >> 8, c = i & 255;
    float v = w1[i];
    int idx = (c >> 5) * 4096 + o * 32 + ((((c >> 3) & 3) ^ (o & 3)) << 3) + (c & 7);
    blob[idx] = f2bf(v);
  } else {
    int i2 = i - 32768;
    int a = i2 >> 7, o = i2 & 127;
    float v = w2[i2];
    int idx = 32768 + (o >> 5) * 512 + a * 32 + ((((o >> 3) & 3) ^ (a & 3)) << 3) + (o & 7);
    blob[idx] = f2bf(v);
  }
}

// ---------------------------------------------------------------------------
// Fused. Grid: 1024 blocks x 512 thr (8 waves = 4 px-groups x 2 o-half
// waves). Per px-group: GEMM1 split A/B over o; hid transpose to shared
// 4KB; sync; wave A does GEMM2+softplus -> Ab; sync; both waves split the
// attractor 32/32 bins. LDS per pg: hid 4096 + Ab 1280 = 5376; block 21504.
// ---------------------------------------------------------------------------
__global__ __launch_bounds__(512, 8) void zoed_fused(
    const float* __restrict__ x, const float* __restrict__ bprev,
    const float* __restrict__ b1, const float* __restrict__ b2,
    const unsigned short* __restrict__ wblob, float* __restrict__ out) {
  __shared__ __align__(16) char smem[21504];

  const int t = threadIdx.x;
  const int lane = t & 63;
  const int l15 = lane & 15;
  const int quad = lane >> 4;
  const int wv = t >> 6;   // 0..7
  const int pg = wv >> 1;  // px-group 0..3
  const int half = wv & 1; // o-half: A=0 (o 0..63), B=1 (o 64..127)
  const int sw = ((quad ^ (l15 & 3)) << 4);

  const int blk = blockIdx.x;
  const int n = blk >> 8;
  const int p0 = ((blk & 255) << 6) + pg * 16;  // this px-group's 16-px base

  char* hid = smem + pg * 5376;         // 16px x 128o bf16, frag layout
  char* Ab = smem + pg * 5376 + 4096;   // 16px x 16attr f32, 80B rows

  // x: thread (l15=px, quad=k-subgroup) loads ch = kb*32 + quad*8 + j
  const float* xb = x + (size_t)(n * 256 + quad * 8) * HW + p0 + l15;
  // w1 frag base for this wave's o-half (tiles half*4 + tm)
  const char* wb = (const char*)wblob + half * 4096 + l15 * 64 + sw;

  f32x4_t acc[4];
#pragma unroll
  for (int i = 0; i < 4; i++) acc[i] = (f32x4_t){0.f, 0.f, 0.f, 0.f};

  // ---- GEMM1: 8 K-chunks, 4 MFMA each (this wave's 4 o-tiles) ----
#pragma unroll
  for (int kb = 0; kb < 8; ++kb) {
    float xv[8];
#pragma unroll
    for (int j = 0; j < 8; j++) xv[j] = xb[(size_t)(kb * 32 + j) * HW];
    u32x4_t v = {cvtpk(xv[0], xv[1]), cvtpk(xv[2], xv[3]),
                 cvtpk(xv[4], xv[5]), cvtpk(xv[6], xv[7])};
    bf16x8_t bfm = __builtin_bit_cast(bf16x8_t, v);
#pragma unroll
    for (int tm = 0; tm < 4; tm++) {
      bf16x8_t af = *(const bf16x8_t*)(wb + kb * 8192 + tm * 1024);
      acc[tm] = __builtin_amdgcn_mfma_f32_16x16x32_bf16(af, bfm, acc[tm],
                                                        0, 0, 0);
    }
  }

  // ---- hidden epilogue: relu(acc + b1) -> bf16 -> hid (this wave's kcs) ----
#pragma unroll
  for (int tm = 0; tm < 4; tm++) {
    f32x4_t b1v = *(const f32x4_t*)(b1 + half * 64 + tm * 16 + quad * 4);
    f32x4_t h = acc[tm] + b1v;
    h[0] = fmaxf(h[0], 0.f);
    h[1] = fmaxf(h[1], 0.f);
    h[2] = fmaxf(h[2], 0.f);
    h[3] = fmaxf(h[3], 0.f);
    int tg = half * 4 + tm;          // global o-tile 0..7
    int kc = tg >> 1;                // hid chunk 0..3
    int g = (tm & 1) * 2 + (quad >> 1);
    int off8 = (quad & 1) * 8;
    unsigned int* dst = (unsigned int*)(hid + kc * 1024 + l15 * 64 +
                                        ((g ^ (l15 & 3)) << 4) + off8);
    dst[0] = cvtpk(h[0], h[1]);
    dst[1] = cvtpk(h[2], h[3]);
  }

  // ---- bprev for this wave's 32 bins (bin = half*32 + quad*8 + b); issue
  // before the barrier so latency hides under sync + GEMM2 ----
  size_t obase = (size_t)(n * 64 + half * 32 + quad * 8) * HW + p0 + l15;
  const float* bp = bprev + obase;
  float bpr[8];
#pragma unroll
  for (int b = 0; b < 8; b++) bpr[b] = bp[(size_t)b * HW];

  __syncthreads();  // hid complete (both halves)

  // ---- GEMM2 (wave A only): A(16attr x 16px) = softplus(w2@hid + b2) ----
  if (half == 0) {
    f32x4_t acc2 = (f32x4_t){0.f, 0.f, 0.f, 0.f};
#pragma unroll
    for (int kc = 0; kc < 4; kc++) {
      bf16x8_t a2 = *(const bf16x8_t*)((const char*)wblob + 65536 +
                                       kc * 1024 + l15 * 64 + sw);
      bf16x8_t bh = *(const bf16x8_t*)(hid + kc * 1024 + l15 * 64 + sw);
      acc2 = __builtin_amdgcn_mfma_f32_16x16x32_bf16(a2, bh, acc2, 0, 0, 0);
    }
    f32x4_t b2v = *(const f32x4_t*)(b2 + quad * 4);
    f32x4_t z = acc2 + b2v;
    f32x4_t spv;
#pragma unroll
    for (int r = 0; r < 4; r++) {
      float zz = z[r];
      spv[r] = fmaxf(zz, 0.f) + log1pf(__expf(-fabsf(zz)));  // stable softplus
    }
    // A[attr quad*4+r][px l15]; 80B rows break bank aliasing
    *(f32x4_t*)(Ab + l15 * 80 + quad * 16) = spv;
  }
  __syncthreads();  // Ab ready

  // ---- redistribute: each lane grabs all 16 A of its px, as f32x2 pairs ----
  f32x2_t av2[8];
#pragma unroll
  for (int q = 0; q < 4; q++) {
    f32x4_t v = *(const f32x4_t*)(Ab + l15 * 80 + q * 16);
    av2[q * 2] = (f32x2_t){v[0], v[1]};
    av2[q * 2 + 1] = (f32x2_t){v[2], v[3]};
  }
  // ---- attractor: this wave's 8 bins/lane (32 bins/wave), pk-f32 math ----
  const f32x2_t K2 = {EXP2K, EXP2K};
  float* o1 = out + obase;
  float* o2 = o1 + (size_t)256 * HW;
#pragma unroll
  for (int b = 0; b < 8; b++) {
    float c = bpr[b];
    f32x2_t c2 = {c, c};
    f32x2_t d0 = {0.f, 0.f}, d1 = {0.f, 0.f};
#pragma unroll
    for (int k = 0; k < 4; k++) {
      f32x2_t dx = av2[k] - c2;
      f32x2_t tt = dx * K2;
      f32x2_t arg = tt * dx;
      f32x2_t e = {exp2a(arg[0]), exp2a(arg[1])};
      d0 = e * dx + d0;
    }
#pragma unroll
    for (int k = 4; k < 8; k++) {
      f32x2_t dx = av2[k] - c2;
      f32x2_t tt = dx * K2;
      f32x2_t arg = tt * dx;
      f32x2_t e = {exp2a(arg[0]), exp2a(arg[1])};
      d1 = e * dx + d1;
    }
    f32x2_t ds = d0 + d1;
    float r = c + (ds[0] + ds[1]);
    __builtin_nontemporal_store(r, o1 + (size_t)b * HW);
    __builtin_nontemporal_store(r, o2 + (size_t)b * HW);
  }
}

extern "C" void kernel_launch(void* const* d_in, const int* in_sizes, int n_in,
                              void* d_out, int out_size, void* d_ws,
                              size_t ws_size, hipStream_t stream) {
  const float* x = (const float*)d_in[0];      // 4*256*128*128
  const float* bprev = (const float*)d_in[1];  // 4*64*128*128
  const float* w1 = (const float*)d_in[2];     // 128*256
  const float* b1 = (const float*)d_in[3];     // 128
  const float* w2 = (const float*)d_in[4];     // 16*128
  const float* b2 = (const float*)d_in[5];     // 16
  float* outp = (float*)d_out;                 // 2 * 4194304
  unsigned short* blob = (unsigned short*)d_ws;  // 69632 B used

  zoed_prep<<<136, 256, 0, stream>>>(w1, w2, blob);
  zoed_fused<<<1024, 512, 0, stream>>>(x, bprev, b1, b2, blob, outp);
}